// Round 4
// baseline (13.741 us; speedup 1.0000x reference)
//
#include <hip/hip_runtime.h>
#include <math.h>

#define H1 1024
#define H2 512
#define NB_H1 1024            // block-per-h1-output
#define NB_GH2 384            // 384 blocks x 4 waves = 1536 gh2 rows
#define NB_K1 (NB_H1 + NB_GH2)

__device__ __forceinline__ float sigmoidf_(float x) { return 1.0f / (1.0f + __expf(-x)); }
__device__ __forceinline__ float dot4(float4 a, float4 b) {
    return a.x * b.x + a.y * b.y + a.z * b.z + a.w * b.w;
}
__device__ __forceinline__ float wave_sum(float v) {
#pragma unroll
    for (int o = 32; o; o >>= 1) v += __shfl_xor(v, o, 64);
    return v;
}

// Kernel 1:
//   blocks [0, 1024): block-per-h1-output. 256 threads; thread t owns float4 #t
//     of each of the 6 length-1024 rows. Wave shuffle + LDS cross-wave reduce.
//   blocks [1024, 1408): wave-per-row gh2 = h2_in . w_hh2[row] + b_hh2[row].
__global__ __launch_bounds__(256) void gru_k1(
    const int* __restrict__ ids,
    const float* __restrict__ h1_in,
    const float* __restrict__ h2_in,
    const float* __restrict__ emb,
    const float* __restrict__ w_ih1,
    const float* __restrict__ w_hh1,
    const float* __restrict__ b_ih1,
    const float* __restrict__ b_hh1,
    const float* __restrict__ w_hh2,
    const float* __restrict__ b_hh2,
    float* __restrict__ d_out,
    float* __restrict__ gh2_ws)
{
    const int t = threadIdx.x;
    const int wave = t >> 6, lane = t & 63;
    const int b = blockIdx.x;

    if (b < NB_H1) {
        __shared__ float red[6][4];
        const int j = b;
        // Hoisted uniform loads (s_loads) — overlap the streaming loop.
        const float bxr = b_ih1[j], bxz = b_ih1[j + H1], bxn = b_ih1[j + 2 * H1];
        const float bhr = b_hh1[j], bhz = b_hh1[j + H1], bhn = b_hh1[j + 2 * H1];
        const float hprev = h1_in[j];

        const float* xrow = emb + (size_t)ids[0] * H1;
        const float4 x4 = ((const float4*)xrow)[t];      // 256 float4 = row
        const float4 h4 = ((const float4*)h1_in)[t];

        float acc[6];
#pragma unroll
        for (int g = 0; g < 3; ++g) {
            const float4 a = ((const float4*)(w_ih1 + (size_t)(g * H1 + j) * H1))[t];
            const float4 c = ((const float4*)(w_hh1 + (size_t)(g * H1 + j) * H1))[t];
            acc[g]     = dot4(x4, a);
            acc[3 + g] = dot4(h4, c);
        }
#pragma unroll
        for (int g = 0; g < 6; ++g) {
            const float v = wave_sum(acc[g]);
            if (lane == 0) red[g][wave] = v;
        }
        __syncthreads();
        if (t == 0) {
            float s[6];
#pragma unroll
            for (int g = 0; g < 6; ++g)
                s[g] = red[g][0] + red[g][1] + red[g][2] + red[g][3];
            const float r = sigmoidf_(s[0] + bxr + s[3] + bhr);
            const float z = sigmoidf_(s[1] + bxz + s[4] + bhz);
            const float n = tanhf(s[2] + bxn + r * (s[5] + bhn));
            d_out[H2 + j] = (1.0f - z) * n + z * hprev;   // h1 at flat offset 512
        }
    } else {
        const int row = (b - NB_H1) * 4 + wave;           // [0, 1536)
        const float bias = b_hh2[row];                     // uniform per wave
        float acc = 0.0f;
#pragma unroll
        for (int k = 0; k < 2; ++k) {
            const int idx = lane + 64 * k;                 // 128 float4 = 512 floats
            const float4 h4 = ((const float4*)h2_in)[idx];
            const float4 wv = ((const float4*)(w_hh2 + (size_t)row * H2))[idx];
            acc += dot4(h4, wv);
        }
        acc = wave_sum(acc);
        if (lane == 0) gh2_ws[row] = acc + bias;
    }
}

// Kernel 2: 512 blocks, block-per-h2-output. Only the 3 w_ih2 dots (vs h1)
// remain; gh2 comes precomputed from d_ws.
__global__ __launch_bounds__(256) void gru_k2(
    const float* __restrict__ h2_in,
    const float* __restrict__ w_ih2,
    const float* __restrict__ b_ih2,
    const float* __restrict__ gh2_ws,
    float* __restrict__ d_out)
{
    __shared__ float red[3][4];
    const int t = threadIdx.x;
    const int wave = t >> 6, lane = t & 63;
    const int j = blockIdx.x;                             // [0, 512)

    // Hoisted uniform loads.
    const float bxr = b_ih2[j], bxz = b_ih2[j + H2], bxn = b_ih2[j + 2 * H2];
    const float hr = gh2_ws[j], hz = gh2_ws[j + H2], hn = gh2_ws[j + 2 * H2];
    const float hprev = h2_in[j];

    const float* h1v = d_out + H2;                        // written by gru_k1
    const float4 hh = ((const float4*)h1v)[t];            // 256 float4 = 1024 floats

    float acc[3];
#pragma unroll
    for (int g = 0; g < 3; ++g) {
        const float4 a = ((const float4*)(w_ih2 + (size_t)(g * H2 + j) * H1))[t];
        acc[g] = dot4(hh, a);
    }
#pragma unroll
    for (int g = 0; g < 3; ++g) {
        const float v = wave_sum(acc[g]);
        if (lane == 0) red[g][wave] = v;
    }
    __syncthreads();
    if (t == 0) {
        const float gx0 = red[0][0] + red[0][1] + red[0][2] + red[0][3];
        const float gx1 = red[1][0] + red[1][1] + red[1][2] + red[1][3];
        const float gx2 = red[2][0] + red[2][1] + red[2][2] + red[2][3];
        const float r = sigmoidf_(gx0 + bxr + hr);
        const float z = sigmoidf_(gx1 + bxz + hz);
        const float n = tanhf(gx2 + bxn + r * hn);
        const float h = (1.0f - z) * n + z * hprev;
        d_out[j] = h;                // output (== h2)
        d_out[3 * H2 + j] = h;       // h2 at flat offset 1536
    }
}

extern "C" void kernel_launch(void* const* d_in, const int* in_sizes, int n_in,
                              void* d_out, int out_size, void* d_ws, size_t ws_size,
                              hipStream_t stream) {
    const int*   ids   = (const int*)d_in[0];
    const float* h1_in = (const float*)d_in[1];
    const float* h2_in = (const float*)d_in[2];
    const float* emb   = (const float*)d_in[3];
    const float* w_ih1 = (const float*)d_in[4];
    const float* w_hh1 = (const float*)d_in[5];
    const float* b_ih1 = (const float*)d_in[6];
    const float* b_hh1 = (const float*)d_in[7];
    const float* w_ih2 = (const float*)d_in[8];
    const float* w_hh2 = (const float*)d_in[9];
    const float* b_ih2 = (const float*)d_in[10];
    const float* b_hh2 = (const float*)d_in[11];
    float* out = (float*)d_out;
    float* gh2 = (float*)d_ws;   // 1536 floats, fully rewritten by k1 each launch

    gru_k1<<<NB_K1, 256, 0, stream>>>(ids, h1_in, h2_in, emb,
                                      w_ih1, w_hh1, b_ih1, b_hh1,
                                      w_hh2, b_hh2, out, gh2);
    gru_k2<<<H2, 256, 0, stream>>>(h2_in, w_ih2, b_ih2, gh2, out);
}